// Round 1
// baseline (706.914 us; speedup 1.0000x reference)
//
#include <hip/hip_runtime.h>
#include <math.h>

#define N_NODES 20000
#define N_EDGES 320000
#define DD 128
#define ND (N_NODES * DD)   // 2,560,000

// ---------------- CSR build ----------------

__global__ void count_kernel(const int* __restrict__ rows, int* __restrict__ cnt) {
    int e = blockIdx.x * blockDim.x + threadIdx.x;
    if (e < N_EDGES) atomicAdd(&cnt[rows[e]], 1);
}

__global__ __launch_bounds__(1024) void scan_kernel(const int* __restrict__ cnt,
                                                    int* __restrict__ row_start,
                                                    int* __restrict__ cursor) {
    __shared__ int part[1024];
    const int t = threadIdx.x;
    const int CH = (N_NODES + 1023) / 1024;  // 20
    int lo = t * CH, hi = min(lo + CH, N_NODES);
    int s = 0;
    for (int i = lo; i < hi; ++i) s += cnt[i];
    part[t] = s;
    __syncthreads();
    for (int off = 1; off < 1024; off <<= 1) {
        int v = (t >= off) ? part[t - off] : 0;
        __syncthreads();
        if (t >= off) part[t] += v;
        __syncthreads();
    }
    int run = (t > 0) ? part[t - 1] : 0;
    for (int i = lo; i < hi; ++i) {
        row_start[i] = run;
        cursor[i] = run;
        run += cnt[i];
    }
    if (t == 1023) row_start[N_NODES] = part[1023];
}

__global__ void scatter_kernel(const int* __restrict__ rows, const int* __restrict__ cols,
                               const float* __restrict__ vals, int* __restrict__ cursor,
                               float2* __restrict__ epack) {
    int e = blockIdx.x * blockDim.x + threadIdx.x;
    if (e >= N_EDGES) return;
    int r = rows[e];
    int p = atomicAdd(&cursor[r], 1);
    epack[p] = make_float2(vals[e], __int_as_float(cols[e]));
}

// ---------------- f(z) = LayerNorm(K*z + A z) : one wave per row ----------------

__global__ __launch_bounds__(256) void feval_kernel(const float* __restrict__ z,
                                                    const float* __restrict__ Kd,
                                                    const float* __restrict__ lnw,
                                                    const float* __restrict__ lnb,
                                                    const int* __restrict__ row_start,
                                                    const float2* __restrict__ epack,
                                                    float* __restrict__ out) {
    int gtid = blockIdx.x * blockDim.x + threadIdx.x;
    int r = gtid >> 6;          // one wave (64 lanes) per row
    int lane = threadIdx.x & 63;
    if (r >= N_NODES) return;
    int d0 = lane * 2;          // each lane owns 2 consecutive dims

    float2 zv = *(const float2*)(z + (size_t)r * DD + d0);
    float k = Kd[r];
    float acc0 = k * zv.x, acc1 = k * zv.y;

    int e0 = row_start[r], e1 = row_start[r + 1];
    for (int e = e0; e < e1; ++e) {
        float2 cv = epack[e];                    // wave-uniform broadcast load
        int c = __float_as_int(cv.y);
        float2 zc = *(const float2*)(z + (size_t)c * DD + d0);
        acc0 = fmaf(cv.x, zc.x, acc0);
        acc1 = fmaf(cv.x, zc.y, acc1);
    }

    // wave-level LayerNorm stats over 128 values (2 per lane)
    float s = acc0 + acc1;
    float sq = acc0 * acc0 + acc1 * acc1;
#pragma unroll
    for (int off = 32; off; off >>= 1) {
        s += __shfl_xor(s, off, 64);
        sq += __shfl_xor(sq, off, 64);
    }
    float mu = s * (1.0f / DD);
    float var = sq * (1.0f / DD) - mu * mu;
    float rstd = rsqrtf(var + 1e-5f);

    float2 wv = *(const float2*)(lnw + d0);
    float2 bv = *(const float2*)(lnb + d0);
    float2 ov;
    ov.x = wv.x * (acc0 - mu) * rstd + bv.x;
    ov.y = wv.y * (acc1 - mu) * rstd + bv.y;
    *(float2*)(out + (size_t)r * DD + d0) = ov;
}

// ---------------- Anderson reductions ----------------

struct Cols10 { const float* f[5]; const float* z[5]; };
struct Cols5  { const float* f[5]; };

__device__ __forceinline__ float dot4(float4 a, float4 b) {
    return a.x * b.x + a.y * b.y + a.z * b.z + a.w * b.w;
}

__global__ __launch_bounds__(256) void reduce_kernel(Cols10 cols, float* __restrict__ red) {
    const int ND4 = ND / 4;
    float acc[14];
#pragma unroll
    for (int k = 0; k < 14; ++k) acc[k] = 0.f;

    for (int j = blockIdx.x * blockDim.x + threadIdx.x; j < ND4; j += gridDim.x * blockDim.x) {
        float4 G[5];
#pragma unroll
        for (int c = 0; c < 5; ++c) {
            float4 fv = ((const float4*)cols.f[c])[j];
            float4 zv = ((const float4*)cols.z[c])[j];
            G[c] = make_float4(fv.x - zv.x, fv.y - zv.y, fv.z - zv.z, fv.w - zv.w);
        }
        float4 dg[4];
#pragma unroll
        for (int a = 0; a < 4; ++a)
            dg[a] = make_float4(G[a + 1].x - G[a].x, G[a + 1].y - G[a].y,
                                G[a + 1].z - G[a].z, G[a + 1].w - G[a].w);
        int k = 0;
#pragma unroll
        for (int a = 0; a < 4; ++a)
#pragma unroll
            for (int b = a; b < 4; ++b) acc[k++] += dot4(dg[a], dg[b]);
#pragma unroll
        for (int a = 0; a < 4; ++a) acc[10 + a] += dot4(dg[a], G[4]);
    }

    // wave reduce
#pragma unroll
    for (int off = 32; off; off >>= 1)
#pragma unroll
        for (int k = 0; k < 14; ++k) acc[k] += __shfl_xor(acc[k], off, 64);

    __shared__ float sh[4][14];
    int wave = threadIdx.x >> 6, lane = threadIdx.x & 63;
    if (lane == 0)
#pragma unroll
        for (int k = 0; k < 14; ++k) sh[wave][k] = acc[k];
    __syncthreads();
    if (threadIdx.x == 0) {
#pragma unroll
        for (int k = 0; k < 14; ++k)
            atomicAdd(&red[k], sh[0][k] + sh[1][k] + sh[2][k] + sh[3][k]);
    }
}

// H = dG^T dG + 0.1 I ; solve H gamma = dG^T g_last (4x4, one thread)
__global__ void solve_kernel(const float* __restrict__ red, float* __restrict__ gam) {
    if (threadIdx.x != 0 || blockIdx.x != 0) return;
    float A[4][4], b[4];
    int k = 0;
    for (int a = 0; a < 4; ++a)
        for (int c = a; c < 4; ++c) { A[a][c] = red[k]; A[c][a] = red[k]; ++k; }
    for (int a = 0; a < 4; ++a) A[a][a] += 0.1f;
    for (int a = 0; a < 4; ++a) b[a] = red[10 + a];

    // Gaussian elimination with partial pivoting
    for (int col = 0; col < 4; ++col) {
        int piv = col;
        float best = fabsf(A[col][col]);
        for (int rr = col + 1; rr < 4; ++rr) {
            float m = fabsf(A[rr][col]);
            if (m > best) { best = m; piv = rr; }
        }
        if (piv != col) {
            for (int c2 = 0; c2 < 4; ++c2) { float t = A[col][c2]; A[col][c2] = A[piv][c2]; A[piv][c2] = t; }
            float t = b[col]; b[col] = b[piv]; b[piv] = t;
        }
        float inv = 1.0f / A[col][col];
        for (int rr = col + 1; rr < 4; ++rr) {
            float m = A[rr][col] * inv;
            for (int c2 = col; c2 < 4; ++c2) A[rr][c2] -= m * A[col][c2];
            b[rr] -= m * b[col];
        }
    }
    float g[4];
    for (int rr = 3; rr >= 0; --rr) {
        float s = b[rr];
        for (int c2 = rr + 1; c2 < 4; ++c2) s -= A[rr][c2] * g[c2];
        g[rr] = s / A[rr][rr];
    }
    bool fin = isfinite(g[0]) && isfinite(g[1]) && isfinite(g[2]) && isfinite(g[3]);
    gam[0] = g[0]; gam[1] = g[1]; gam[2] = g[2]; gam[3] = g[3];
    gam[4] = fin ? 1.0f : 0.0f;
}

// z = 0.5*f + 0.5*(f - dF*gamma) = f - 0.5*dF*gamma   (or f if gamma non-finite)
__global__ __launch_bounds__(256) void update_kernel(Cols5 c, const float* __restrict__ gam,
                                                     float* __restrict__ zout) {
    const int ND4 = ND / 4;
    int j = blockIdx.x * blockDim.x + threadIdx.x;
    if (j >= ND4) return;
    float g0 = gam[0], g1 = gam[1], g2 = gam[2], g3 = gam[3], flag = gam[4];
    float4 f0 = ((const float4*)c.f[0])[j];
    float4 f1 = ((const float4*)c.f[1])[j];
    float4 f2 = ((const float4*)c.f[2])[j];
    float4 f3 = ((const float4*)c.f[3])[j];
    float4 f4 = ((const float4*)c.f[4])[j];
    float4 o;
    if (flag != 0.0f) {
        o.x = f4.x - 0.5f * ((f1.x - f0.x) * g0 + (f2.x - f1.x) * g1 + (f3.x - f2.x) * g2 + (f4.x - f3.x) * g3);
        o.y = f4.y - 0.5f * ((f1.y - f0.y) * g0 + (f2.y - f1.y) * g1 + (f3.y - f2.y) * g2 + (f4.y - f3.y) * g3);
        o.z = f4.z - 0.5f * ((f1.z - f0.z) * g0 + (f2.z - f1.z) * g1 + (f3.z - f2.z) * g2 + (f4.z - f3.z) * g3);
        o.w = f4.w - 0.5f * ((f1.w - f0.w) * g0 + (f2.w - f1.w) * g1 + (f3.w - f2.w) * g2 + (f4.w - f3.w) * g3);
    } else {
        o = f4;
    }
    ((float4*)zout)[j] = o;
}

// ---------------- host ----------------

extern "C" void kernel_launch(void* const* d_in, const int* in_sizes, int n_in,
                              void* d_out, int out_size, void* d_ws, size_t ws_size,
                              hipStream_t stream) {
    const float* x_init = (const float*)d_in[0];
    const float* Kd     = (const float*)d_in[1];
    const float* vals   = (const float*)d_in[2];
    const float* lnw    = (const float*)d_in[3];
    const float* lnb    = (const float*)d_in[4];
    const int*   rows   = (const int*)d_in[5];
    const int*   cols   = (const int*)d_in[6];
    // d_in[7] = batch (unused), d_in[8] = max_iter (constant 8, hardcoded)
    float* out = (float*)d_out;

    char* p = (char*)d_ws;
    auto carve = [&](size_t bytes) -> void* {
        void* r = (void*)p;
        p += (bytes + 255) & ~(size_t)255;
        return r;
    };
    float*  Fh        = (float*)carve((size_t)6 * ND * 4);   // rolling f_t history, slot t%6
    float*  red       = (float*)carve(256);                  // [0..13] sums, [16..20] gamma+flag
    int*    row_start = (int*)carve((N_NODES + 1) * 4);
    int*    cursor    = (int*)carve(N_NODES * 4);
    int*    cnt       = (int*)carve(N_NODES * 4);
    float2* epack     = (float2*)carve((size_t)N_EDGES * 8);
    float*  gam       = red + 16;
    float*  zA        = out;  // d_out doubles as storage for Anderson z7 (overwritten at t=7)

    // CSR build (once per launch, reused by all 8 iterations)
    hipMemsetAsync(cnt, 0, N_NODES * 4, stream);
    count_kernel<<<(N_EDGES + 255) / 256, 256, 0, stream>>>(rows, cnt);
    scan_kernel<<<1, 1024, 0, stream>>>(cnt, row_start, cursor);
    scatter_kernel<<<(N_EDGES + 255) / 256, 256, 0, stream>>>(rows, cols, vals, cursor, epack);

    auto Fslot = [&](int t) -> float* { return Fh + (size_t)(t % 6) * ND; };

    for (int t = 0; t < 8; ++t) {
        // z_t: x_init at t=0; f_{t-1} for plain steps; Anderson z7 (in d_out) at t=7
        const float* zsrc = (t == 0) ? x_init : (t <= 6 ? Fslot(t - 1) : zA);
        feval_kernel<<<(N_NODES * 64 + 255) / 256, 256, 0, stream>>>(
            zsrc, Kd, lnw, lnb, row_start, epack, Fslot(t));

        if (t >= 6) {
            // history columns are iterations t-4 .. t ; z_{tc} = f_{tc-1} except z7
            Cols10 rc;
            for (int c2 = 0; c2 < 5; ++c2) {
                int tc = t - 4 + c2;
                rc.f[c2] = Fslot(tc);
                rc.z[c2] = (tc == 7) ? (const float*)zA : (const float*)Fslot(tc - 1);
            }
            hipMemsetAsync(red, 0, 14 * 4, stream);
            reduce_kernel<<<640, 256, 0, stream>>>(rc, red);
            solve_kernel<<<1, 64, 0, stream>>>(red, gam);

            Cols5 uc;
            for (int c2 = 0; c2 < 5; ++c2) uc.f[c2] = Fslot(t - 4 + c2);
            float* zdst = (t == 6) ? zA : out;
            update_kernel<<<(ND / 4 + 255) / 256, 256, 0, stream>>>(uc, gam, zdst);
        }
    }
}

// Round 2
// 361.230 us; speedup vs baseline: 1.9570x; 1.9570x over previous
//
#include <hip/hip_runtime.h>
#include <math.h>

#define N_NODES 20000
#define N_EDGES 320000
#define DD 128
#define ND (N_NODES * DD)   // 2,560,000
#define ND4 (ND / 4)        // 640,000

// ---------------- CSR build ----------------

__global__ void count_kernel(const int* __restrict__ rows, int* __restrict__ cnt) {
    int e = blockIdx.x * blockDim.x + threadIdx.x;
    if (e < N_EDGES) atomicAdd(&cnt[rows[e]], 1);
}

__global__ __launch_bounds__(1024) void scan_kernel(const int* __restrict__ cnt,
                                                    int* __restrict__ row_start,
                                                    int* __restrict__ cursor) {
    __shared__ int part[1024];
    const int t = threadIdx.x;
    const int CH = (N_NODES + 1023) / 1024;  // 20
    int lo = t * CH, hi = min(lo + CH, N_NODES);
    int s = 0;
    for (int i = lo; i < hi; ++i) s += cnt[i];
    part[t] = s;
    __syncthreads();
    for (int off = 1; off < 1024; off <<= 1) {
        int v = (t >= off) ? part[t - off] : 0;
        __syncthreads();
        if (t >= off) part[t] += v;
        __syncthreads();
    }
    int run = (t > 0) ? part[t - 1] : 0;
    for (int i = lo; i < hi; ++i) {
        row_start[i] = run;
        cursor[i] = run;
        run += cnt[i];
    }
    if (t == 1023) row_start[N_NODES] = part[1023];
}

__global__ void scatter_kernel(const int* __restrict__ rows, const int* __restrict__ cols,
                               const float* __restrict__ vals, int* __restrict__ cursor,
                               float2* __restrict__ epack) {
    int e = blockIdx.x * blockDim.x + threadIdx.x;
    if (e >= N_EDGES) return;
    int r = rows[e];
    int p = atomicAdd(&cursor[r], 1);
    epack[p] = make_float2(vals[e], __int_as_float(cols[e]));
}

// ---------------- f(z) = LayerNorm(K*z + A z) : one wave per row ----------------

__global__ __launch_bounds__(256) void feval_kernel(const float* __restrict__ z,
                                                    const float* __restrict__ Kd,
                                                    const float* __restrict__ lnw,
                                                    const float* __restrict__ lnb,
                                                    const int* __restrict__ row_start,
                                                    const float2* __restrict__ epack,
                                                    float* __restrict__ out) {
    int gtid = blockIdx.x * blockDim.x + threadIdx.x;
    int r = gtid >> 6;          // one wave (64 lanes) per row
    int lane = threadIdx.x & 63;
    if (r >= N_NODES) return;
    int d0 = lane * 2;          // each lane owns 2 consecutive dims

    float2 zv = *(const float2*)(z + (size_t)r * DD + d0);
    float k = Kd[r];
    float acc0 = k * zv.x, acc1 = k * zv.y;

    int e0 = row_start[r], e1 = row_start[r + 1];
    // lanes cooperatively load up to 64 edges, broadcast via shfl, gather z rows
    for (int base = e0; base < e1; base += 64) {
        int ew = base + lane;
        float2 my_e = (ew < e1) ? epack[ew] : make_float2(0.0f, 0.0f);
        float my_val = my_e.x;
        int my_col = __float_as_int(my_e.y);
        int m = min(64, e1 - base);
        int i = 0;
        for (; i + 4 <= m; i += 4) {
            int c0 = __shfl(my_col, i, 64);
            int c1 = __shfl(my_col, i + 1, 64);
            int c2 = __shfl(my_col, i + 2, 64);
            int c3 = __shfl(my_col, i + 3, 64);
            float v0 = __shfl(my_val, i, 64);
            float v1 = __shfl(my_val, i + 1, 64);
            float v2 = __shfl(my_val, i + 2, 64);
            float v3 = __shfl(my_val, i + 3, 64);
            float2 z0 = *(const float2*)(z + (size_t)c0 * DD + d0);
            float2 z1 = *(const float2*)(z + (size_t)c1 * DD + d0);
            float2 z2 = *(const float2*)(z + (size_t)c2 * DD + d0);
            float2 z3 = *(const float2*)(z + (size_t)c3 * DD + d0);
            acc0 = fmaf(v0, z0.x, acc0); acc1 = fmaf(v0, z0.y, acc1);
            acc0 = fmaf(v1, z1.x, acc0); acc1 = fmaf(v1, z1.y, acc1);
            acc0 = fmaf(v2, z2.x, acc0); acc1 = fmaf(v2, z2.y, acc1);
            acc0 = fmaf(v3, z3.x, acc0); acc1 = fmaf(v3, z3.y, acc1);
        }
        for (; i < m; ++i) {
            int c = __shfl(my_col, i, 64);
            float v = __shfl(my_val, i, 64);
            float2 zc = *(const float2*)(z + (size_t)c * DD + d0);
            acc0 = fmaf(v, zc.x, acc0);
            acc1 = fmaf(v, zc.y, acc1);
        }
    }

    // wave-level LayerNorm stats over 128 values (2 per lane)
    float s = acc0 + acc1;
    float sq = acc0 * acc0 + acc1 * acc1;
#pragma unroll
    for (int off = 32; off; off >>= 1) {
        s += __shfl_xor(s, off, 64);
        sq += __shfl_xor(sq, off, 64);
    }
    float mu = s * (1.0f / DD);
    float var = sq * (1.0f / DD) - mu * mu;
    float rstd = rsqrtf(var + 1e-5f);

    float2 wv = *(const float2*)(lnw + d0);
    float2 bv = *(const float2*)(lnb + d0);
    float2 ov;
    ov.x = wv.x * (acc0 - mu) * rstd + bv.x;
    ov.y = wv.y * (acc1 - mu) * rstd + bv.y;
    *(float2*)(out + (size_t)r * DD + d0) = ov;
}

// ---------------- Anderson reductions ----------------

struct Cols10 { const float* f[5]; const float* z[5]; };
struct Cols5  { const float* f[5]; };

__device__ __forceinline__ float dot4(float4 a, float4 b) {
    return a.x * b.x + a.y * b.y + a.z * b.z + a.w * b.w;
}
__device__ __forceinline__ float4 sub4(float4 a, float4 b) {
    return make_float4(a.x - b.x, a.y - b.y, a.z - b.z, a.w - b.w);
}

// 625 blocks x 256 threads; each thread owns exactly 4 j's (2 phases x 2),
// each phase issues 20 independent float4 loads before any use (ILP).
#define RED_T 160000
__global__ __launch_bounds__(256) void reduce_kernel(Cols10 cols, float* __restrict__ red) {
    int tid = blockIdx.x * 256 + threadIdx.x;
    float acc[14];
#pragma unroll
    for (int k = 0; k < 14; ++k) acc[k] = 0.f;

#pragma unroll
    for (int ph = 0; ph < 2; ++ph) {
        int ja = tid + (2 * ph) * RED_T;
        int jb = ja + RED_T;
        float4 fa[5], za[5], fb[5], zb[5];
#pragma unroll
        for (int c = 0; c < 5; ++c) {
            fa[c] = ((const float4*)cols.f[c])[ja];
            za[c] = ((const float4*)cols.z[c])[ja];
            fb[c] = ((const float4*)cols.f[c])[jb];
            zb[c] = ((const float4*)cols.z[c])[jb];
        }
        float4 Ga[5], Gb[5];
#pragma unroll
        for (int c = 0; c < 5; ++c) { Ga[c] = sub4(fa[c], za[c]); Gb[c] = sub4(fb[c], zb[c]); }
        float4 dga[4], dgb[4];
#pragma unroll
        for (int a = 0; a < 4; ++a) { dga[a] = sub4(Ga[a + 1], Ga[a]); dgb[a] = sub4(Gb[a + 1], Gb[a]); }
        int k = 0;
#pragma unroll
        for (int a = 0; a < 4; ++a)
#pragma unroll
            for (int b = a; b < 4; ++b) { acc[k] += dot4(dga[a], dga[b]) + dot4(dgb[a], dgb[b]); ++k; }
#pragma unroll
        for (int a = 0; a < 4; ++a) acc[10 + a] += dot4(dga[a], Ga[4]) + dot4(dgb[a], Gb[4]);
    }

    // wave reduce
#pragma unroll
    for (int off = 32; off; off >>= 1)
#pragma unroll
        for (int k = 0; k < 14; ++k) acc[k] += __shfl_xor(acc[k], off, 64);

    __shared__ float sh[4][14];
    int wave = threadIdx.x >> 6, lane = threadIdx.x & 63;
    if (lane == 0)
#pragma unroll
        for (int k = 0; k < 14; ++k) sh[wave][k] = acc[k];
    __syncthreads();
    if (threadIdx.x < 14) {
        int k = threadIdx.x;
        // counters padded to separate 64B lines -> no same-line atomic pileup
        atomicAdd(&red[k * 16], sh[0][k] + sh[1][k] + sh[2][k] + sh[3][k]);
    }
}

// H = dG^T dG + 0.1 I ; solve H gamma = dG^T g_last (4x4, one thread)
__global__ void solve_kernel(const float* __restrict__ red, float* __restrict__ gam) {
    if (threadIdx.x != 0 || blockIdx.x != 0) return;
    float A[4][4], b[4];
    int k = 0;
    for (int a = 0; a < 4; ++a)
        for (int c = a; c < 4; ++c) { A[a][c] = red[k * 16]; A[c][a] = red[k * 16]; ++k; }
    for (int a = 0; a < 4; ++a) A[a][a] += 0.1f;
    for (int a = 0; a < 4; ++a) b[a] = red[(10 + a) * 16];

    for (int col = 0; col < 4; ++col) {
        int piv = col;
        float best = fabsf(A[col][col]);
        for (int rr = col + 1; rr < 4; ++rr) {
            float m = fabsf(A[rr][col]);
            if (m > best) { best = m; piv = rr; }
        }
        if (piv != col) {
            for (int c2 = 0; c2 < 4; ++c2) { float t = A[col][c2]; A[col][c2] = A[piv][c2]; A[piv][c2] = t; }
            float t = b[col]; b[col] = b[piv]; b[piv] = t;
        }
        float inv = 1.0f / A[col][col];
        for (int rr = col + 1; rr < 4; ++rr) {
            float m = A[rr][col] * inv;
            for (int c2 = col; c2 < 4; ++c2) A[rr][c2] -= m * A[col][c2];
            b[rr] -= m * b[col];
        }
    }
    float g[4];
    for (int rr = 3; rr >= 0; --rr) {
        float s = b[rr];
        for (int c2 = rr + 1; c2 < 4; ++c2) s -= A[rr][c2] * g[c2];
        g[rr] = s / A[rr][rr];
    }
    bool fin = isfinite(g[0]) && isfinite(g[1]) && isfinite(g[2]) && isfinite(g[3]);
    gam[0] = g[0]; gam[1] = g[1]; gam[2] = g[2]; gam[3] = g[3];
    gam[4] = fin ? 1.0f : 0.0f;
}

// z = 0.5*f + 0.5*(f - dF*gamma) = f - 0.5*dF*gamma   (or f if gamma non-finite)
__global__ __launch_bounds__(256) void update_kernel(Cols5 c, const float* __restrict__ gam,
                                                     float* __restrict__ zout) {
    int j = blockIdx.x * blockDim.x + threadIdx.x;
    if (j >= ND4) return;
    float g0 = gam[0], g1 = gam[1], g2 = gam[2], g3 = gam[3], flag = gam[4];
    float4 f0 = ((const float4*)c.f[0])[j];
    float4 f1 = ((const float4*)c.f[1])[j];
    float4 f2 = ((const float4*)c.f[2])[j];
    float4 f3 = ((const float4*)c.f[3])[j];
    float4 f4 = ((const float4*)c.f[4])[j];
    float4 o;
    if (flag != 0.0f) {
        o.x = f4.x - 0.5f * ((f1.x - f0.x) * g0 + (f2.x - f1.x) * g1 + (f3.x - f2.x) * g2 + (f4.x - f3.x) * g3);
        o.y = f4.y - 0.5f * ((f1.y - f0.y) * g0 + (f2.y - f1.y) * g1 + (f3.y - f2.y) * g2 + (f4.y - f3.y) * g3);
        o.z = f4.z - 0.5f * ((f1.z - f0.z) * g0 + (f2.z - f1.z) * g1 + (f3.z - f2.z) * g2 + (f4.z - f3.z) * g3);
        o.w = f4.w - 0.5f * ((f1.w - f0.w) * g0 + (f2.w - f1.w) * g1 + (f3.w - f2.w) * g2 + (f4.w - f3.w) * g3);
    } else {
        o = f4;
    }
    ((float4*)zout)[j] = o;
}

// ---------------- host ----------------

extern "C" void kernel_launch(void* const* d_in, const int* in_sizes, int n_in,
                              void* d_out, int out_size, void* d_ws, size_t ws_size,
                              hipStream_t stream) {
    const float* x_init = (const float*)d_in[0];
    const float* Kd     = (const float*)d_in[1];
    const float* vals   = (const float*)d_in[2];
    const float* lnw    = (const float*)d_in[3];
    const float* lnb    = (const float*)d_in[4];
    const int*   rows   = (const int*)d_in[5];
    const int*   cols   = (const int*)d_in[6];
    float* out = (float*)d_out;

    char* p = (char*)d_ws;
    auto carve = [&](size_t bytes) -> void* {
        void* r = (void*)p;
        p += (bytes + 255) & ~(size_t)255;
        return r;
    };
    float*  Fh        = (float*)carve((size_t)6 * ND * 4);   // rolling f_t history, slot t%6
    float*  red       = (float*)carve(4096);                 // 14 counters, stride-16 floats
    float*  gam       = (float*)carve(256);                  // gamma[0..3] + finite flag
    int*    row_start = (int*)carve((N_NODES + 1) * 4);
    int*    cursor    = (int*)carve(N_NODES * 4);
    int*    cnt       = (int*)carve(N_NODES * 4);
    float2* epack     = (float2*)carve((size_t)N_EDGES * 8);
    float*  zA        = out;  // d_out doubles as storage for Anderson z7 (overwritten at t=7)

    // CSR build (once per launch, reused by all 8 iterations)
    hipMemsetAsync(cnt, 0, N_NODES * 4, stream);
    count_kernel<<<(N_EDGES + 255) / 256, 256, 0, stream>>>(rows, cnt);
    scan_kernel<<<1, 1024, 0, stream>>>(cnt, row_start, cursor);
    scatter_kernel<<<(N_EDGES + 255) / 256, 256, 0, stream>>>(rows, cols, vals, cursor, epack);

    auto Fslot = [&](int t) -> float* { return Fh + (size_t)(t % 6) * ND; };

    for (int t = 0; t < 8; ++t) {
        const float* zsrc = (t == 0) ? x_init : (t <= 6 ? Fslot(t - 1) : zA);
        feval_kernel<<<(N_NODES * 64 + 255) / 256, 256, 0, stream>>>(
            zsrc, Kd, lnw, lnb, row_start, epack, Fslot(t));

        if (t >= 6) {
            Cols10 rc;
            for (int c2 = 0; c2 < 5; ++c2) {
                int tc = t - 4 + c2;
                rc.f[c2] = Fslot(tc);
                rc.z[c2] = (tc == 7) ? (const float*)zA : (const float*)Fslot(tc - 1);
            }
            hipMemsetAsync(red, 0, 14 * 16 * 4, stream);
            reduce_kernel<<<625, 256, 0, stream>>>(rc, red);
            solve_kernel<<<1, 64, 0, stream>>>(red, gam);

            Cols5 uc;
            for (int c2 = 0; c2 < 5; ++c2) uc.f[c2] = Fslot(t - 4 + c2);
            float* zdst = (t == 6) ? zA : out;
            update_kernel<<<(ND4 + 255) / 256, 256, 0, stream>>>(uc, gam, zdst);
        }
    }
}